// Round 1
// baseline (418.482 us; speedup 1.0000x reference)
//
#include <hip/hip_runtime.h>

// y[b,c,h,w] = x[b,c,h,w] * gamma[c] + beta[c]
// x: (8, 128, 256, 256) fp32. HW plane = 65536 elements per channel.
// One thread per float4; c = (elem_idx >> 16) & 127 is wave-uniform.

#define HW_SHIFT 16      // log2(256*256)
#define C_MASK   127     // NUM_FEATURE - 1

__global__ __launch_bounds__(256) void scale_kernel(
    const float4* __restrict__ x4,
    const float* __restrict__ gamma,
    const float* __restrict__ beta,
    float4* __restrict__ y4)
{
    const long long i4 = (long long)blockIdx.x * blockDim.x + threadIdx.x;
    const long long elem = i4 << 2;                 // first element of this float4
    const int c = (int)((elem >> HW_SHIFT) & C_MASK);

    const float g = gamma[c];
    const float b = beta[c];

    float4 v = x4[i4];
    v.x = fmaf(v.x, g, b);
    v.y = fmaf(v.y, g, b);
    v.z = fmaf(v.z, g, b);
    v.w = fmaf(v.w, g, b);
    y4[i4] = v;
}

extern "C" void kernel_launch(void* const* d_in, const int* in_sizes, int n_in,
                              void* d_out, int out_size, void* d_ws, size_t ws_size,
                              hipStream_t stream) {
    const float* x     = (const float*)d_in[0];
    const float* gamma = (const float*)d_in[1];
    const float* beta  = (const float*)d_in[2];
    float* y           = (float*)d_out;

    const long long n  = (long long)out_size;   // 8*128*256*256 = 67108864
    const long long n4 = n >> 2;                // 16777216 float4s
    const int block = 256;
    const long long grid = (n4 + block - 1) / block;  // 65536 blocks

    scale_kernel<<<(dim3)(unsigned)grid, block, 0, stream>>>(
        (const float4*)x, gamma, beta, (float4*)y);
}